// Round 1
// baseline (1254.029 us; speedup 1.0000x reference)
//
#include <hip/hip_runtime.h>

// Integer softmax (I-BERT shift-exp style), S = 2048 per row.
// One 64-lane wave per row; 32 elements/lane held in registers (8x float4).
// Reductions via __shfl_xor across the wave. No LDS, no __syncthreads.

#define ROW_S 2048
#define ELEMS_PER_LANE 32   // 2048 / 64
#define WAVES_PER_BLOCK 4
#define BLOCK_THREADS 256

__global__ __launch_bounds__(BLOCK_THREADS)
void intsoftmax_kernel(const float* __restrict__ x,
                       const float* __restrict__ s_pre_p,
                       float* __restrict__ out,
                       int nrows)
{
    const int wave = threadIdx.x >> 6;
    const int lane = threadIdx.x & 63;
    const int row  = blockIdx.x * WAVES_PER_BLOCK + wave;

    // trailing scalar output: out_sf = 1/2^(BIT_WIDTH-1) = 1/128
    if (blockIdx.x == 0 && threadIdx.x == 0)
        out[(size_t)nrows * ROW_S] = 0.0078125f;

    if (row >= nrows) return;

    const float s_pre = s_pre_p[0];
    const float x0    = floorf(-1.0f / s_pre);   // e.g. -20 for s=0.05
    const float nx0   = 15.0f * x0;              // N_SHIFT * x0 (exact)

    const float* __restrict__ xr   = x   + (size_t)row * ROW_S;
    float*       __restrict__ orow = out + (size_t)row * ROW_S;

    // ---- pass A: load row (coalesced float4), x_int = x / s_pre, track max ----
    float v[ELEMS_PER_LANE];
    float m = -3.402823466e38f;
    #pragma unroll
    for (int c = 0; c < 8; ++c) {
        float4 f = reinterpret_cast<const float4*>(xr)[c * 64 + lane];
        float a0 = f.x / s_pre;   // IEEE correctly-rounded div, matches reference
        float a1 = f.y / s_pre;
        float a2 = f.z / s_pre;
        float a3 = f.w / s_pre;
        v[c*4+0] = a0; v[c*4+1] = a1; v[c*4+2] = a2; v[c*4+3] = a3;
        m = fmaxf(m, fmaxf(fmaxf(a0, a1), fmaxf(a2, a3)));
    }
    #pragma unroll
    for (int off = 32; off; off >>= 1)
        m = fmaxf(m, __shfl_xor(m, off, 64));

    // ---- pass B: shift-exp per element, exact integer row-sum ----
    int lsum = 0;
    #pragma unroll
    for (int i = 0; i < ELEMS_PER_LANE; ++i) {
        float t = v[i] - m;
        // x + floor(x/2) - floor(x/16)   (div by 2^k == mul by 2^-k, exact)
        t = t + floorf(t * 0.5f);
        t = t - floorf(t * 0.0625f);
        t = fmaxf(t, nx0);                 // clamp at n*x0 = -300
        float q = t / x0;                  // correctly-rounded div
        q = floorf(q);                     // q in [0, 15]
        float r = t - x0 * q;              // x0*q exact (small ints) -> fma-safe
        float e = r * 0.5f - x0;           // in (10, 20]
        int   iq = (int)q;
        float p2 = __int_as_float((142 - iq) << 23);   // 2^(15-q), exact
        float ei = fmaxf(floorf(e * p2), 0.0f);        // <= 655360, exact
        v[i] = ei;
        lsum += (int)ei;
    }
    #pragma unroll
    for (int off = 32; off; off >>= 1)
        lsum += __shfl_xor(lsum, off, 64);
    // max possible row sum = 2048*655360 = 1.34e9 < 2^31 (no INT32_MAX clamp hit)

    float sumf   = (float)lsum;                        // correctly-rounded sum
    float factor = floorf(2147483648.0f / sumf);       // fp32(INT32_MAX)=2^31

    // ---- pass C: scale to 8-bit fixed point, write out (coalesced float4) ----
    const float inv224 = 1.0f / 16777216.0f;           // 2^-24, exact
    const float out_sf = 0.0078125f;                   // 1/128
    #pragma unroll
    for (int c = 0; c < 8; ++c) {
        float4 o;
        o.x = floorf((v[c*4+0] * factor) * inv224) * out_sf;
        o.y = floorf((v[c*4+1] * factor) * inv224) * out_sf;
        o.z = floorf((v[c*4+2] * factor) * inv224) * out_sf;
        o.w = floorf((v[c*4+3] * factor) * inv224) * out_sf;
        reinterpret_cast<float4*>(orow)[c * 64 + lane] = o;
    }
}

extern "C" void kernel_launch(void* const* d_in, const int* in_sizes, int n_in,
                              void* d_out, int out_size, void* d_ws, size_t ws_size,
                              hipStream_t stream) {
    const float* x     = (const float*)d_in[0];
    const float* s_pre = (const float*)d_in[1];
    float* out = (float*)d_out;

    const int nrows = in_sizes[0] / ROW_S;              // 4*12*2048 = 98304
    const int nblocks = (nrows + WAVES_PER_BLOCK - 1) / WAVES_PER_BLOCK;

    intsoftmax_kernel<<<nblocks, BLOCK_THREADS, 0, stream>>>(x, s_pre, out, nrows);
}